// Round 4
// baseline (325.312 us; speedup 1.0000x reference)
//
#include <hip/hip_runtime.h>
#include <hip/hip_bf16.h>

// Self-attention: B=4, S=4096, D=512, f32 in/out, bf16 MFMA internally.
// cvt(q,k,v)->bf16 (z=3); W transpose->bf16 (z=4); proj GEMM (NT, z=3);
// VWT[b] = (v_proj @ Wo)^T via NT GEMM (A=WTO, B=VP) -- kills btrans+final;
// per batch: E=qp@kp^T (bf16), softmax -> P[b]; out = P@VWT^T + bo (f32).
// GEMM: 8-phase deep pipeline. BM=256, 8 waves (2x4), BK=64, double-buffered
// 128/96 KiB LDS, per-phase {ds_read; lgkmcnt(0); barrier; setprio(1);
// 16 MFMA; setprio(0); barrier}; stage issued once per K-tile after the
// all-reads-retired barrier; counted vmcnt (8 / 6), never 0 in main loop.
// BN=256 for square E GEMM; BN=128 for the N=512 GEMMs (occupancy).

typedef __attribute__((ext_vector_type(8))) short bf16x8;
typedef __attribute__((ext_vector_type(4))) float f32x4;
typedef __attribute__((ext_vector_type(8))) unsigned short u16x8;

#define DEVI static __device__ __forceinline__

DEVI unsigned short f2b(float x) {
  __hip_bfloat16 h = __float2bfloat16(x);
  return __builtin_bit_cast(unsigned short, h);
}
DEVI float b2f(unsigned short x) {
  return __builtin_bit_cast(float, (unsigned)x << 16);
}

typedef const void __attribute__((address_space(1)))* gptr_t;
typedef void __attribute__((address_space(3)))* lptr_t;

DEVI void gload_lds16(const void* g, void* l) {
  __builtin_amdgcn_global_load_lds((gptr_t)g, (lptr_t)l, 16, 0, 0);
}

// ------------- f32 -> bf16 convert, z selects (k,v,q) -> contiguous dst ---
__global__ void cvt3_f32_to_bf16(const float* __restrict__ s0,
                                 const float* __restrict__ s1,
                                 const float* __restrict__ s2,
                                 u16x8* __restrict__ dst, int n8) {
  int i = blockIdx.x * 256 + threadIdx.x;
  if (i >= n8) return;
  const float* src = blockIdx.z == 0 ? s0 : (blockIdx.z == 1 ? s1 : s2);
  const float4* s4 = (const float4*)src;
  float4 a = s4[2 * i], b = s4[2 * i + 1];
  u16x8 o;
  o[0] = f2b(a.x); o[1] = f2b(a.y); o[2] = f2b(a.z); o[3] = f2b(a.w);
  o[4] = f2b(b.x); o[5] = f2b(b.y); o[6] = f2b(b.z); o[7] = f2b(b.w);
  dst[(long)blockIdx.z * n8 + i] = o;
}

// ---- W [512,512] f32 -> WT [512,512] bf16 transpose, z selects W ---------
__global__ void wtrans4_f32(const float* __restrict__ w0,
                            const float* __restrict__ w1,
                            const float* __restrict__ w2,
                            const float* __restrict__ w3,
                            unsigned short* __restrict__ WT) {
  __shared__ unsigned short s[32][33];
  const float* W = blockIdx.z == 0 ? w0 : (blockIdx.z == 1 ? w1
                   : (blockIdx.z == 2 ? w2 : w3));
  unsigned short* dst = WT + (long)blockIdx.z * 512 * 512;
  int tx = threadIdx.x, ty = threadIdx.y;   // (32,8)
  int bx = blockIdx.x, by = blockIdx.y;
#pragma unroll
  for (int i = 0; i < 32; i += 8)
    s[ty + i][tx] = f2b(W[(by * 32 + ty + i) * 512 + bx * 32 + tx]);
  __syncthreads();
#pragma unroll
  for (int i = 0; i < 32; i += 8)
    dst[(bx * 32 + ty + i) * 512 + by * 32 + tx] = s[tx][ty + i];
}

// ------------- 8-phase NT GEMM: C[M,N] = A[M,K]*B[N,K]^T (+bias) ----------
template <int BN, bool OUT_BF16, bool HAS_BIAS>
__global__ __launch_bounds__(512, 2) void gemm8p(
    const unsigned short* __restrict__ A,
    const unsigned short* __restrict__ B,
    void* __restrict__ Cv,
    const float* __restrict__ bias0,
    const float* __restrict__ bias1,
    const float* __restrict__ bias2,
    int M, int N, int K, long sA, long sB, long sC) {
  constexpr int WN = BN / 4;             // wave col-tile: 64 or 32
  constexpr int NFRAG = WN / 16;         // 4 or 2
  constexpr int MHALF = (BN == 256) ? 2 : 1;  // m-half phases per ks
  constexpr int MPP = 8 / MHALF;         // m-frags per phase: 4 or 8
  constexpr int BLOADS = BN / 64;        // 4 or 2 stage loads for B

  __shared__ unsigned short As[2][256 * 64];
  __shared__ unsigned short Bs[2][BN * 64];

  // XCD-bijective swizzle (nwg % 8 == 0 for every launch here).
  const int gx = gridDim.x, gy = gridDim.y;
  const int nwg = gx * gy * gridDim.z;
  const int orig = (blockIdx.z * gy + blockIdx.y) * gx + blockIdx.x;
  const int qch = nwg >> 3;
  const int wg = (orig & 7) * qch + (orig >> 3);
  const int bx = wg % gx;
  const int tmp = wg / gx;
  const int by = tmp % gy;
  const int bz = tmp / gy;

  const unsigned short* Ab = A + (long)bz * sA;
  const unsigned short* Bb = B + (long)bz * sB;

  const int t = threadIdx.x;
  const int lane = t & 63;
  const int wid = t >> 6;                // 8 waves: 2 (M) x 4 (N)
  const int wrow = wid >> 2, wcol = wid & 3;
  const int lr = lane & 15, lk = lane >> 4;
  const long row0 = (long)by * 256;
  const long col0 = (long)bx * BN;

  f32x4 acc[8][NFRAG] = {};

  auto stage = [&](int buf, int k0) {
#pragma unroll
    for (int p = 0; p < 4; ++p) {        // A: 256x64 = 32 KiB
      int gg = p * 512 + t;
      int r = gg >> 3, c = gg & 7;
      gload_lds16(Ab + (row0 + r) * (long)K + k0 + (c ^ (r & 7)) * 8,
                  (char*)As[buf] + gg * 16);
    }
#pragma unroll
    for (int p = 0; p < BLOADS; ++p) {   // B: BNx64
      int gg = p * 512 + t;
      int r = gg >> 3, c = gg & 7;
      gload_lds16(Bb + (col0 + r) * (long)K + k0 + (c ^ (r & 7)) * 8,
                  (char*)Bs[buf] + gg * 16);
    }
  };
  auto vm_wait = [&](bool staged) {
    if (staged) {
      if constexpr (BN == 256)
        asm volatile("s_waitcnt vmcnt(8)" ::: "memory");
      else
        asm volatile("s_waitcnt vmcnt(6)" ::: "memory");
    } else {
      asm volatile("s_waitcnt vmcnt(0)" ::: "memory");
    }
  };

  // Process one K-tile from LDS buffer `buf`; optionally stage k0n into the
  // SAME buffer at the last phase (all reads of it retired by then).
  auto tile = [&](int buf, bool do_stage, int k0n) {
#pragma unroll
    for (int s = 0; s < 2; ++s) {        // k-slice (K=32 each)
      bf16x8 bfr[NFRAG];
#pragma unroll
      for (int h = 0; h < MHALF; ++h) {
        bf16x8 af[MPP];
#pragma unroll
        for (int m = 0; m < MPP; ++m) {
          int rowA = wrow * 128 + (h * MPP + m) * 16 + lr;
          af[m] = *(const bf16x8*)((const char*)As[buf] + rowA * 128 +
                                   ((s * 4 + lk) ^ (rowA & 7)) * 16);
        }
        if (h == 0) {
#pragma unroll
          for (int n = 0; n < NFRAG; ++n) {
            int rowB = wcol * WN + n * 16 + lr;
            bfr[n] = *(const bf16x8*)((const char*)Bs[buf] + rowB * 128 +
                                      ((s * 4 + lk) ^ (rowB & 7)) * 16);
          }
        }
        // All my ds_reads retired before the barrier -> after the barrier
        // every wave's reads of this buffer are retired (stage-safety).
        asm volatile("s_waitcnt lgkmcnt(0)" ::: "memory");
        __builtin_amdgcn_s_barrier();
        const bool last_phase = (s == 1) && (h == MHALF - 1);
        if (last_phase && do_stage) stage(buf, k0n);
        __builtin_amdgcn_s_setprio(1);
#pragma unroll
        for (int m = 0; m < MPP; ++m)
#pragma unroll
          for (int n = 0; n < NFRAG; ++n)
            acc[h * MPP + m][n] = __builtin_amdgcn_mfma_f32_16x16x32_bf16(
                af[m], bfr[n], acc[h * MPP + m][n], 0, 0, 0);
        __builtin_amdgcn_s_setprio(0);
        if (last_phase) vm_wait(do_stage);
        __builtin_amdgcn_s_barrier();
      }
    }
  };

  const int nt = K >> 6;                 // even for all our shapes
  stage(0, 0);
  stage(1, 64);
  vm_wait(true);                         // T0 landed; T1 in flight
  __builtin_amdgcn_s_barrier();
  for (int kt = 0; kt < nt; kt += 2) {
    tile(0, kt + 2 < nt, (kt + 2) << 6);
    tile(1, kt + 3 < nt, (kt + 3) << 6);
  }

  const float* bias = bz == 0 ? bias0 : (bz == 1 ? bias1 : bias2);
#pragma unroll
  for (int m = 0; m < 8; ++m) {
#pragma unroll
    for (int n = 0; n < NFRAG; ++n) {
#pragma unroll
      for (int r = 0; r < 4; ++r) {
        long row = row0 + wrow * 128 + m * 16 + lk * 4 + r;
        long col = col0 + wcol * WN + n * 16 + lr;
        float v = acc[m][n][r];
        if (HAS_BIAS) v += bias[col];
        if (OUT_BF16)
          ((unsigned short*)Cv + bz * sC)[row * N + col] = f2b(v);
        else
          ((float*)Cv + bz * sC)[row * N + col] = v;
      }
    }
  }
}

// ---- row softmax: E [4096,4096] bf16 -> P bf16, scale 1/sqrt(512) --------
__global__ __launch_bounds__(256) void softmax_rows_bf16(
    const unsigned short* __restrict__ E, unsigned short* __restrict__ P) {
  const int S = 4096;
  long row = blockIdx.x;
  const u16x8* e8 = (const u16x8*)(E + row * S);
  int t = threadIdx.x;
  float v[16];
  float m = -3.0e38f;
#pragma unroll
  for (int p = 0; p < 2; ++p) {
    u16x8 x = e8[t + p * 256];
#pragma unroll
    for (int j = 0; j < 8; ++j) {
      float f = b2f((unsigned short)x[j]);
      v[8 * p + j] = f;
      m = fmaxf(m, f);
    }
  }
#pragma unroll
  for (int off = 32; off; off >>= 1) m = fmaxf(m, __shfl_xor(m, off));
  __shared__ float redm[4], reds[4];
  if ((t & 63) == 0) redm[t >> 6] = m;
  __syncthreads();
  m = fmaxf(fmaxf(redm[0], redm[1]), fmaxf(redm[2], redm[3]));
  const float scale = 0.04419417382415922f;  // 1/sqrt(512)
  float s = 0.f;
#pragma unroll
  for (int i = 0; i < 16; ++i) {
    v[i] = __expf((v[i] - m) * scale);
    s += v[i];
  }
#pragma unroll
  for (int off = 32; off; off >>= 1) s += __shfl_xor(s, off);
  if ((t & 63) == 0) reds[t >> 6] = s;
  __syncthreads();
  float inv = 1.0f / (reds[0] + reds[1] + reds[2] + reds[3]);
  u16x8* p8 = (u16x8*)(P + row * S);
#pragma unroll
  for (int p = 0; p < 2; ++p) {
    u16x8 o;
#pragma unroll
    for (int j = 0; j < 8; ++j) o[j] = f2b(v[8 * p + j] * inv);
    p8[t + p * 256] = o;
  }
}

extern "C" void kernel_launch(void* const* d_in, const int* in_sizes, int n_in,
                              void* d_out, int out_size, void* d_ws, size_t ws_size,
                              hipStream_t stream) {
  const float* k_in = (const float*)d_in[0];
  const float* v_in = (const float*)d_in[1];
  const float* q_in = (const float*)d_in[2];
  const float* Wk = (const float*)d_in[3];
  const float* bk = (const float*)d_in[4];
  const float* Wv = (const float*)d_in[5];
  const float* bv = (const float*)d_in[6];
  const float* Wq = (const float*)d_in[7];
  const float* bq = (const float*)d_in[8];
  const float* Wo = (const float*)d_in[9];
  const float* bo = (const float*)d_in[10];

  const int B = 4, S = 4096, D = 512;
  const long BS = (long)B * S;      // 16384
  const size_t MB = 1024 * 1024;
  if (ws_size < 226 * MB) return;   // leaves d_out poisoned -> visible failure

  // Workspace (226 MiB):
  //   0..128   P0..P3 (32 MiB each; early: XK 0..16, XV 16..32, XQ 32..48)
  //   128..176 KP, VP, QP (16 MiB each, uniform stride)
  //   176..192 VWT (4 MiB per batch: [512,4096] bf16)
  //   192..224 EBUF (bf16 S*S, reused per batch)
  //   224..226 WTK,WTV,WTQ,WTO
  char* ws = (char*)d_ws;
  unsigned short* P    = (unsigned short*)(ws + 0);
  unsigned short* XK   = (unsigned short*)(ws + 0);
  unsigned short* KP   = (unsigned short*)(ws + 128 * MB);
  unsigned short* VP   = (unsigned short*)(ws + 144 * MB);
  unsigned short* QP   = (unsigned short*)(ws + 160 * MB);
  unsigned short* VWT  = (unsigned short*)(ws + 176 * MB);
  unsigned short* EBUF = (unsigned short*)(ws + 192 * MB);
  unsigned short* WTK  = (unsigned short*)(ws + 224 * MB);
  unsigned short* WTO  = WTK + 3L * 512 * 512;

  int n8 = (int)(BS * D / 8);
  cvt3_f32_to_bf16<<<dim3((n8 + 255) / 256, 1, 3), 256, 0, stream>>>(
      k_in, v_in, q_in, (u16x8*)XK, n8);

  wtrans4_f32<<<dim3(16, 16, 4), dim3(32, 8), 0, stream>>>(
      Wk, Wv, Wq, Wo, WTK);

  // K/V/Q projections, z=3: (X[z], WT[z]) -> {KP,VP,QP}[z], bias per z.
  gemm8p<128, true, true><<<dim3(D / 128, BS / 256, 3), 512, 0, stream>>>(
      XK, WTK, KP, bk, bv, bq, (int)BS, D, D,
      BS * D, (long)512 * 512, BS * D);

  // VWT[b] = (v_proj[b] @ Wo)^T  == NT(A=WTO [512,512], B=VP[b] [4096,512]).
  gemm8p<128, true, false><<<dim3(S / 128, D / 256, 4), 512, 0, stream>>>(
      WTO, VP, VWT, nullptr, nullptr, nullptr, D, S, D,
      0, (long)S * D, (long)S * D);

  for (int b = 0; b < B; ++b) {
    gemm8p<256, true, false><<<dim3(S / 256, S / 256, 1), 512, 0, stream>>>(
        QP + (long)b * S * D, KP + (long)b * S * D, EBUF,
        nullptr, nullptr, nullptr, S, S, D, 0, 0, 0);
    softmax_rows_bf16<<<S, 256, 0, stream>>>(EBUF, P + (long)b * S * S);
  }

  // out[b] = P[b] @ VWT[b]^T + bo  (f32 straight to d_out), z=4.
  gemm8p<128, false, true><<<dim3(D / 128, S / 256, 4), 512, 0, stream>>>(
      P, VWT, d_out, bo, bo, bo, S, D, S,
      (long)S * S, (long)S * D, (long)S * D);
}

// Round 5
// 298.433 us; speedup vs baseline: 1.0901x; 1.0901x over previous
//
#include <hip/hip_runtime.h>
#include <hip/hip_bf16.h>

// Self-attention: B=4, S=4096, D=512, f32 in/out, bf16 MFMA internally.
// cvt(q,k,v)->bf16 (z=3); W transpose->bf16 (z=4); proj GEMM (NT, z=3);
// VWT[b] = (v_proj @ Wo)^T via NT GEMM; E=qp@kp^T -> P region (z=4);
// softmax in-place on P; out = P@VWT^T + bo -> d_out (f32, z=4).
// GEMM schedule (m201-style): per phase {ds_read issue; [stage]; barrier;
// (compiler lgkm waits) MFMA under setprio}; stage at phase 1 into a buffer
// whose reads retired a full tile ago; BN=128 -> TRIPLE-buffered LDS with
// counted vmcnt(6) (never 0 mid-loop); BN=256 -> double-buffered.

typedef __attribute__((ext_vector_type(8))) short bf16x8;
typedef __attribute__((ext_vector_type(4))) float f32x4;
typedef __attribute__((ext_vector_type(8))) unsigned short u16x8;

#define DEVI static __device__ __forceinline__

DEVI unsigned short f2b(float x) {
  __hip_bfloat16 h = __float2bfloat16(x);
  return __builtin_bit_cast(unsigned short, h);
}
DEVI float b2f(unsigned short x) {
  return __builtin_bit_cast(float, (unsigned)x << 16);
}

typedef const void __attribute__((address_space(1)))* gptr_t;
typedef void __attribute__((address_space(3)))* lptr_t;

DEVI void gload_lds16(const void* g, void* l) {
  __builtin_amdgcn_global_load_lds((gptr_t)g, (lptr_t)l, 16, 0, 0);
}

// ------------- f32 -> bf16 convert, z selects (k,v,q) -> contiguous dst ---
__global__ void cvt3_f32_to_bf16(const float* __restrict__ s0,
                                 const float* __restrict__ s1,
                                 const float* __restrict__ s2,
                                 u16x8* __restrict__ dst, int n8) {
  int i = blockIdx.x * 256 + threadIdx.x;
  if (i >= n8) return;
  const float* src = blockIdx.z == 0 ? s0 : (blockIdx.z == 1 ? s1 : s2);
  const float4* s4 = (const float4*)src;
  float4 a = s4[2 * i], b = s4[2 * i + 1];
  u16x8 o;
  o[0] = f2b(a.x); o[1] = f2b(a.y); o[2] = f2b(a.z); o[3] = f2b(a.w);
  o[4] = f2b(b.x); o[5] = f2b(b.y); o[6] = f2b(b.z); o[7] = f2b(b.w);
  dst[(long)blockIdx.z * n8 + i] = o;
}

// ---- W [512,512] f32 -> WT [512,512] bf16 transpose, z selects W ---------
__global__ void wtrans4_f32(const float* __restrict__ w0,
                            const float* __restrict__ w1,
                            const float* __restrict__ w2,
                            const float* __restrict__ w3,
                            unsigned short* __restrict__ WT) {
  __shared__ unsigned short s[32][33];
  const float* W = blockIdx.z == 0 ? w0 : (blockIdx.z == 1 ? w1
                   : (blockIdx.z == 2 ? w2 : w3));
  unsigned short* dst = WT + (long)blockIdx.z * 512 * 512;
  int tx = threadIdx.x, ty = threadIdx.y;   // (32,8)
  int bx = blockIdx.x, by = blockIdx.y;
#pragma unroll
  for (int i = 0; i < 32; i += 8)
    s[ty + i][tx] = f2b(W[(by * 32 + ty + i) * 512 + bx * 32 + tx]);
  __syncthreads();
#pragma unroll
  for (int i = 0; i < 32; i += 8)
    dst[(bx * 32 + ty + i) * 512 + by * 32 + tx] = s[tx][ty + i];
}

// ------------- pipelined NT GEMM: C[M,N] = A[M,K]*B[N,K]^T (+bias) --------
template <int BN, bool OUT_BF16, bool HAS_BIAS>
__global__ __launch_bounds__(512, 2) void gemm8p(
    const unsigned short* __restrict__ A,
    const unsigned short* __restrict__ B,
    void* __restrict__ Cv,
    const float* __restrict__ bias0,
    const float* __restrict__ bias1,
    const float* __restrict__ bias2,
    int M, int N, int K, long sA, long sB, long sC) {
  constexpr int WN = BN / 4;             // wave col-tile: 64 or 32
  constexpr int NFRAG = WN / 16;         // 4 or 2
  constexpr int MHALF = (BN == 256) ? 2 : 1;
  constexpr int MPP = 8 / MHALF;         // m-frags per phase: 4 or 8
  constexpr int BLOADS = BN / 64;        // stage loads for B: 4 or 2
  constexpr int NBUF = (BN == 128) ? 3 : 2;

  __shared__ unsigned short As[NBUF][256 * 64];
  __shared__ unsigned short Bs[NBUF][BN * 64];

  // XCD-bijective swizzle (nwg % 8 == 0 for every launch here).
  const int gx = gridDim.x, gy = gridDim.y;
  const int nwg = gx * gy * gridDim.z;
  const int orig = (blockIdx.z * gy + blockIdx.y) * gx + blockIdx.x;
  const int qch = nwg >> 3;
  const int wg = (orig & 7) * qch + (orig >> 3);
  const int bx = wg % gx;
  const int tmp = wg / gx;
  const int by = tmp % gy;
  const int bz = tmp / gy;

  const unsigned short* Ab = A + (long)bz * sA;
  const unsigned short* Bb = B + (long)bz * sB;

  const int t = threadIdx.x;
  const int lane = t & 63;
  const int wid = t >> 6;                // 8 waves: 2 (M) x 4 (N)
  const int wrow = wid >> 2, wcol = wid & 3;
  const int lr = lane & 15, lk = lane >> 4;
  const long row0 = (long)by * 256;
  const long col0 = (long)bx * BN;

  f32x4 acc[8][NFRAG] = {};

  auto stage = [&](int buf, int k0) {
#pragma unroll
    for (int p = 0; p < 4; ++p) {        // A: 256x64 bf16 = 32 KiB
      int gg = p * 512 + t;
      int r = gg >> 3, c = gg & 7;
      gload_lds16(Ab + (row0 + r) * (long)K + k0 + (c ^ (r & 7)) * 8,
                  (char*)As[buf] + gg * 16);
    }
#pragma unroll
    for (int p = 0; p < BLOADS; ++p) {   // B: BNx64
      int gg = p * 512 + t;
      int r = gg >> 3, c = gg & 7;
      gload_lds16(Bb + (col0 + r) * (long)K + k0 + (c ^ (r & 7)) * 8,
                  (char*)Bs[buf] + gg * 16);
    }
  };

  const int nt = K >> 6;
  // Prologue: fill NBUF-1 buffers; wait only for buffer 0.
  stage(0, 0);
  if constexpr (NBUF == 3) {
    stage(1, 64);
    asm volatile("s_waitcnt vmcnt(6)" ::: "memory");
  } else {
    asm volatile("s_waitcnt vmcnt(0)" ::: "memory");
  }
  __builtin_amdgcn_s_barrier();

  int cur = 0, stg = NBUF - 1;
  for (int tt = 0; tt < nt; ++tt) {
    const bool do_stage = (tt + NBUF - 1) < nt;
#pragma unroll
    for (int s = 0; s < 2; ++s) {
      bf16x8 bfr[NFRAG];
#pragma unroll
      for (int h = 0; h < MHALF; ++h) {
        bf16x8 af[MPP];
#pragma unroll
        for (int m = 0; m < MPP; ++m) {
          int rowA = wrow * 128 + (h * MPP + m) * 16 + lr;
          af[m] = *(const bf16x8*)((const char*)As[cur] + rowA * 128 +
                                   ((s * 4 + lk) ^ (rowA & 7)) * 16);
        }
        if (h == 0) {
#pragma unroll
          for (int n = 0; n < NFRAG; ++n) {
            int rowB = wcol * WN + n * 16 + lr;
            bfr[n] = *(const bf16x8*)((const char*)Bs[cur] + rowB * 128 +
                                      ((s * 4 + lk) ^ (rowB & 7)) * 16);
          }
        }
        // Stage tile tt+NBUF-1 into buffer `stg`: its last reads were in
        // tile tt-1 (== tt+NBUF-1 mod NBUF), retired before that tile's
        // closing barrier -> no read/write race by construction.
        if (s == 0 && h == 0 && do_stage) stage(stg, (tt + NBUF - 1) << 6);
        __builtin_amdgcn_sched_barrier(0);
        __builtin_amdgcn_s_barrier();
        // (compiler inserts fine-grained lgkmcnt before each MFMA use)
        __builtin_amdgcn_s_setprio(1);
#pragma unroll
        for (int m = 0; m < MPP; ++m)
#pragma unroll
          for (int n = 0; n < NFRAG; ++n)
            acc[h * MPP + m][n] = __builtin_amdgcn_mfma_f32_16x16x32_bf16(
                af[m], bfr[n], acc[h * MPP + m][n], 0, 0, 0);
        __builtin_amdgcn_s_setprio(0);
        if (s == 1 && h == MHALF - 1) {
          // Tile end: next tile's loads must be LDS-visible to ALL waves
          // after the closing barrier -> per-wave wait BEFORE the barrier.
          if constexpr (NBUF == 3) {
            if (do_stage)
              asm volatile("s_waitcnt vmcnt(6)" ::: "memory");  // counted
            else
              asm volatile("s_waitcnt vmcnt(0)" ::: "memory");  // tail drain
          } else {
            asm volatile("s_waitcnt vmcnt(0)" ::: "memory");    // ~3 phases old
          }
          __builtin_amdgcn_sched_barrier(0);
        }
        __builtin_amdgcn_s_barrier();
      }
    }
    cur = (cur + 1 == NBUF) ? 0 : cur + 1;
    stg = (stg + 1 == NBUF) ? 0 : stg + 1;
  }

  const float* bias = bz == 0 ? bias0 : (bz == 1 ? bias1 : bias2);
#pragma unroll
  for (int m = 0; m < 8; ++m) {
#pragma unroll
    for (int n = 0; n < NFRAG; ++n) {
#pragma unroll
      for (int r = 0; r < 4; ++r) {
        long row = row0 + wrow * 128 + m * 16 + lk * 4 + r;
        long col = col0 + wcol * WN + n * 16 + lr;
        float v = acc[m][n][r];
        if (HAS_BIAS) v += bias[col];
        if (OUT_BF16)
          ((unsigned short*)Cv + bz * sC)[row * N + col] = f2b(v);
        else
          ((float*)Cv + bz * sC)[row * N + col] = v;
      }
    }
  }
}

// ---- in-place row softmax on bf16 [*, 4096], scale 1/sqrt(512) -----------
__global__ __launch_bounds__(256) void softmax_rows_bf16(
    unsigned short* data) {
  const int S = 4096;
  long row = blockIdx.x;
  u16x8* e8 = (u16x8*)(data + row * S);
  int t = threadIdx.x;
  float v[16];
  float m = -3.0e38f;
#pragma unroll
  for (int p = 0; p < 2; ++p) {
    u16x8 x = e8[t + p * 256];
#pragma unroll
    for (int j = 0; j < 8; ++j) {
      float f = b2f((unsigned short)x[j]);
      v[8 * p + j] = f;
      m = fmaxf(m, f);
    }
  }
#pragma unroll
  for (int off = 32; off; off >>= 1) m = fmaxf(m, __shfl_xor(m, off));
  __shared__ float redm[4], reds[4];
  if ((t & 63) == 0) redm[t >> 6] = m;
  __syncthreads();
  m = fmaxf(fmaxf(redm[0], redm[1]), fmaxf(redm[2], redm[3]));
  const float scale = 0.04419417382415922f;  // 1/sqrt(512)
  float s = 0.f;
#pragma unroll
  for (int i = 0; i < 16; ++i) {
    v[i] = __expf((v[i] - m) * scale);
    s += v[i];
  }
#pragma unroll
  for (int off = 32; off; off >>= 1) s += __shfl_xor(s, off);
  if ((t & 63) == 0) reds[t >> 6] = s;
  __syncthreads();
  float inv = 1.0f / (reds[0] + reds[1] + reds[2] + reds[3]);
#pragma unroll
  for (int p = 0; p < 2; ++p) {
    u16x8 o;
#pragma unroll
    for (int j = 0; j < 8; ++j) o[j] = f2b(v[8 * p + j] * inv);
    e8[t + p * 256] = o;
  }
}

extern "C" void kernel_launch(void* const* d_in, const int* in_sizes, int n_in,
                              void* d_out, int out_size, void* d_ws, size_t ws_size,
                              hipStream_t stream) {
  const float* k_in = (const float*)d_in[0];
  const float* v_in = (const float*)d_in[1];
  const float* q_in = (const float*)d_in[2];
  const float* Wk = (const float*)d_in[3];
  const float* bk = (const float*)d_in[4];
  const float* Wv = (const float*)d_in[5];
  const float* bv = (const float*)d_in[6];
  const float* Wq = (const float*)d_in[7];
  const float* bq = (const float*)d_in[8];
  const float* Wo = (const float*)d_in[9];
  const float* bo = (const float*)d_in[10];

  const int B = 4, S = 4096, D = 512;
  const long BS = (long)B * S;      // 16384
  const size_t MB = 1024 * 1024;
  if (ws_size < 226 * MB) return;   // leaves d_out poisoned -> visible failure

  // Workspace (226 MiB):
  //   0..128   P0..P3 (E written here z=4, softmax in-place)
  //            (early: XK 0..16, XV 16..32, XQ 32..48 -- dead after proj)
  //   128..176 KP, VP, QP (16 MiB each, uniform stride)
  //   176..192 VWT (4 MiB per batch: [512,4096]^T layout, bf16)
  //   224..226 WTK,WTV,WTQ,WTO
  char* ws = (char*)d_ws;
  unsigned short* P    = (unsigned short*)(ws + 0);
  unsigned short* XK   = (unsigned short*)(ws + 0);
  unsigned short* KP   = (unsigned short*)(ws + 128 * MB);
  unsigned short* VP   = (unsigned short*)(ws + 144 * MB);
  unsigned short* QP   = (unsigned short*)(ws + 160 * MB);
  unsigned short* VWT  = (unsigned short*)(ws + 176 * MB);
  unsigned short* WTK  = (unsigned short*)(ws + 224 * MB);
  unsigned short* WTO  = WTK + 3L * 512 * 512;

  int n8 = (int)(BS * D / 8);
  cvt3_f32_to_bf16<<<dim3((n8 + 255) / 256, 1, 3), 256, 0, stream>>>(
      k_in, v_in, q_in, (u16x8*)XK, n8);

  wtrans4_f32<<<dim3(16, 16, 4), dim3(32, 8), 0, stream>>>(
      Wk, Wv, Wq, Wo, WTK);

  // K/V/Q projections, z=3: (X[z], WT[z]) -> {KP,VP,QP}[z], bias per z.
  gemm8p<128, true, true><<<dim3(D / 128, BS / 256, 3), 512, 0, stream>>>(
      XK, WTK, KP, bk, bv, bq, (int)BS, D, D,
      BS * D, (long)512 * 512, BS * D);

  // VWT[b] = (v_proj[b] @ Wo)^T == NT(A=WTO [512,512], B=VP[b] [4096,512]).
  gemm8p<128, true, false><<<dim3(S / 128, D / 256, 4), 512, 0, stream>>>(
      WTO, VP, VWT, nullptr, nullptr, nullptr, D, S, D,
      0, (long)S * D, (long)S * D);

  // E[b] = qp[b] @ kp[b]^T -> P region, one z=4 dispatch (1024 blocks).
  gemm8p<256, true, false><<<dim3(S / 256, S / 256, 4), 512, 0, stream>>>(
      QP, KP, P, nullptr, nullptr, nullptr, S, S, D,
      (long)S * D, (long)S * D, (long)S * S);

  // softmax in-place on all 16384 rows.
  softmax_rows_bf16<<<(int)BS, 256, 0, stream>>>(P);

  // out[b] = P[b] @ VWT[b]^T + bo (f32 straight to d_out), z=4.
  gemm8p<128, false, true><<<dim3(D / 128, S / 256, 4), 512, 0, stream>>>(
      P, VWT, d_out, bo, bo, bo, S, D, S,
      (long)S * S, (long)S * D, (long)S * D);
}